// Round 8
// baseline (40.154 us; speedup 1.0000x reference)
//
#include <hip/hip_runtime.h>
#include <cstdint>

#define NPTS 512
#define DIM 256
#define NBLK 256            // 16x16 tiles of 32x32; block b also handles anchors 2b,2b+1
#define TK 32
#define LDSW 132            // padded LDS row stride (floats)
#define MARGIN_F 0.2f
#define FIX_SCALE 1073741824.0   // 2^30
#define SUM_BITS 42
#define CNT_SHIFT 42
#define TAG_SHIFT 56
#define PART_TAG 0x55ull
#define FLAG_MAGIC 0x55AA33CCu

__device__ __forceinline__ uint32_t rotl32(uint32_t x, uint32_t r) {
  return (x << r) | (x >> (32u - r));
}

// JAX threefry2x32, key (0, 42), partitionable mode: bits = out0 ^ out1,
// counter x = (hi32(m)=0, lo32(m)=m). Verified bit-exact (absmax 0.0, r1-r6).
__device__ __forceinline__ uint32_t threefry_bits(uint32_t c1) {
  const uint32_t k0 = 0u, k1 = 42u;
  const uint32_t k2 = k0 ^ k1 ^ 0x1BD11BDAu;
  uint32_t x0 = 0u + k0;
  uint32_t x1 = c1 + k1;
#define TFR(r) { x0 += x1; x1 = rotl32(x1, r); x1 ^= x0; }
  TFR(13u) TFR(15u) TFR(26u) TFR(6u)
  x0 += k1; x1 += k2 + 1u;
  TFR(17u) TFR(29u) TFR(16u) TFR(24u)
  x0 += k2; x1 += k0 + 2u;
  TFR(13u) TFR(15u) TFR(26u) TFR(6u)
  x0 += k0; x1 += k1 + 3u;
  TFR(17u) TFR(29u) TFR(16u) TFR(24u)
  x0 += k1; x1 += k2 + 4u;
  TFR(13u) TFR(15u) TFR(26u) TFR(6u)
  x0 += k2; x1 += k0 + 5u;
#undef TFR
  return x0 ^ x1;
}

// Fused Gram + semi-hard kernel. Grid 256 x 512 threads.
// Phase A: block b computes G tile (b>>4, b&15) (+ dg on diagonal), flags it.
// Phase B: block b waits for its tile-row + diagonal flags, scans anchors
// 2b,2b+1, writes tagged part[b]. Block 0 reduces all parts -> out[0].
// Replay-safe: all gated data is bit-identical each replay, so stale flags
// from a prior replay are harmless; first post-poison call waits properly.
__global__ __launch_bounds__(512) void triplet_fused(
    const float* __restrict__ emb,
    const int* __restrict__ labels,
    float* __restrict__ G,
    float* __restrict__ dg,
    uint32_t* gflag,
    unsigned long long* part,
    float* __restrict__ out)
{
  __shared__ float As[TK][LDSW];
  __shared__ float Bs[TK][LDSW];
  __shared__ float sd0[NPTS];
  __shared__ float sd1[NPTS];
  __shared__ int   slab[NPTS];
  __shared__ int   plist[256];
  __shared__ int   pcnt;
  __shared__ unsigned long long wsum[8], wcnt[8];

  const int b = blockIdx.x;
  const int ti = b >> 4, tj = b & 15;
  const int t = threadIdx.x;
  const int ty = t >> 4;     // 0..31
  const int tx = t & 15;     // 0..15

  // ================= Phase A: Gram tile (verbatim round 6) =================
  float acc0 = 0.f, acc1 = 0.f;
  #pragma unroll
  for (int kh = 0; kh < 2; ++kh) {
    const int koff = kh << 7;   // 0, 128
    __syncthreads();
    #pragma unroll
    for (int q = 0; q < 2; ++q) {
      const int f = t * 2 + q;
      const int r = f >> 5;
      const int c4 = f & 31;
      const float4 va = *reinterpret_cast<const float4*>(emb + (ti * TK + r) * DIM + koff + c4 * 4);
      const float4 vb = *reinterpret_cast<const float4*>(emb + (tj * TK + r) * DIM + koff + c4 * 4);
      *reinterpret_cast<float4*>(&As[r][c4 * 4]) = va;
      *reinterpret_cast<float4*>(&Bs[r][c4 * 4]) = vb;
    }
    __syncthreads();
    #pragma unroll 8
    for (int k4 = 0; k4 < 32; ++k4) {
      const float4 a  = *reinterpret_cast<const float4*>(&As[ty][k4 * 4]);
      const float4 b0 = *reinterpret_cast<const float4*>(&Bs[tx][k4 * 4]);
      const float4 b1 = *reinterpret_cast<const float4*>(&Bs[tx + 16][k4 * 4]);
      acc0 += a.x * b0.x + a.y * b0.y + a.z * b0.z + a.w * b0.w;
      acc1 += a.x * b1.x + a.y * b1.y + a.z * b1.z + a.w * b1.w;
    }
  }
  const int gr = ti * TK + ty;
  const int gc0 = tj * TK + tx;
  G[gr * NPTS + gc0]      = acc0;
  G[gr * NPTS + gc0 + 16] = acc1;
  if (ti == tj) {
    if (ty == tx)           dg[gr] = acc0;
    else if (ty == tx + 16) dg[gr] = acc1;
  }
  __syncthreads();  // drains all this block's stores (vmcnt(0) before barrier)
  if (t == 0) {
    __hip_atomic_store(&gflag[b], FLAG_MAGIC, __ATOMIC_RELEASE,
                       __HIP_MEMORY_SCOPE_AGENT);
  }

  // ============ Phase B prep (no G dependency): labels + plist =============
  const int a0 = b * 2;
  const int a1 = a0 + 1;
  const int wave = t >> 6;
  const int lane = t & 63;

  if (t == 0) pcnt = 0;
  slab[t] = labels[t];
  __syncthreads();
  {
    const int lp = slab[t];
    if (t != a0 && lp == slab[a0]) { int k = atomicAdd(&pcnt, 1); plist[k] = t; }
    if (t != a1 && lp == slab[a1]) { int k = atomicAdd(&pcnt, 1); plist[k] = (1 << 16) | t; }
  }
  __syncthreads();

  // ====== Gate: wait for own tile-row (16) + diagonal (16) producers =======
  if (t < 32) {
    const int src = (t < 16) ? ((ti << 4) + t) : ((t - 16) * 17);
    while (__hip_atomic_load(&gflag[src], __ATOMIC_ACQUIRE,
                             __HIP_MEMORY_SCOPE_AGENT) != FLAG_MAGIC) { }
  }
  __syncthreads();
  __builtin_amdgcn_fence(__ATOMIC_ACQUIRE, "agent");

  // ======= Reconstruct the two sqd rows from Gram + diagonal (6 KB) ========
  {
    const float da0 = dg[a0];
    const float da1 = dg[a1];
    const float dt  = dg[t];
    const float g0 = G[a0 * NPTS + t];
    const float g1 = G[a1 * NPTS + t];
    const float v0 = da0 + dt - 2.f * g0;
    const float v1 = da1 + dt - 2.f * g1;
    sd0[t] = v0 > 0.f ? v0 : 0.f;
    sd1[t] = v1 > 0.f ? v1 : 0.f;
  }
  __syncthreads();

  // ========= Semi-hard scan + threefry argmax (verbatim round 6) ===========
  unsigned long long lsum = 0ull, lcnt = 0ull;
  const int np = pcnt;
  for (int e = wave; e < np; e += 8) {
    const int ent = plist[e];
    const int ai = ent >> 16;
    const int p = ent & 0xffff;
    const float* drp = ai ? sd1 : sd0;
    const int ag = ai ? a1 : a0;
    const int la = slab[ag];
    const float dap = drp[p];
    const float hi = dap + MARGIN_F;
    const uint32_t base = ((uint32_t)ag << 18) | ((uint32_t)p << 9);

    int bestKey = -1, bestJ = 0;
    #pragma unroll
    for (int k = 0; k < 8; ++k) {
      const int j = lane + (k << 6);
      const float dj = drp[j];
      if (slab[j] != la && dj > dap && dj < hi) {
        const int key = (int)(threefry_bits(base + (uint32_t)j) >> 9);
        if (key > bestKey) { bestKey = key; bestJ = j; }
      }
    }
    #pragma unroll
    for (int m = 32; m; m >>= 1) {
      const int ok = __shfl_xor(bestKey, m);
      const int oj = __shfl_xor(bestJ, m);
      if (ok > bestKey || (ok == bestKey && oj < bestJ)) { bestKey = ok; bestJ = oj; }
    }
    if (lane == 0 && bestKey >= 0) {
      const float term = (dap - drp[bestJ]) + MARGIN_F;
      lsum += (unsigned long long)((double)term * FIX_SCALE + 0.5);
      lcnt += 1ull;
    }
  }

  // ===== Block reduce (integer, fixed order) -> tagged part slot ===========
  if (lane == 0) { wsum[wave] = lsum; wcnt[wave] = lcnt; }
  __syncthreads();
  if (t == 0) {
    unsigned long long s = 0ull, c = 0ull;
    #pragma unroll
    for (int w = 0; w < 8; ++w) { s += wsum[w]; c += wcnt[w]; }
    const unsigned long long val = (PART_TAG << TAG_SHIFT) | (c << CNT_SHIFT) | s;
    __hip_atomic_store(&part[b], val, __ATOMIC_RELEASE, __HIP_MEMORY_SCOPE_AGENT);
  }

  // ===== Block 0, wave 0: gather all 256 tagged parts, finalize loss =======
  if (b == 0 && wave == 0) {
    unsigned long long s = 0ull, c = 0ull;
    #pragma unroll
    for (int k = 0; k < NBLK / 64; ++k) {
      const int slot = lane * (NBLK / 64) + k;
      unsigned long long v;
      do {
        v = __hip_atomic_load(&part[slot], __ATOMIC_ACQUIRE,
                              __HIP_MEMORY_SCOPE_AGENT);
      } while ((v >> TAG_SHIFT) != PART_TAG);
      s += v & ((1ull << SUM_BITS) - 1ull);
      c += (v >> CNT_SHIFT) & 0x3FFFull;
    }
    #pragma unroll
    for (int m = 32; m; m >>= 1) {
      s += __shfl_xor(s, m);
      c += __shfl_xor(c, m);
    }
    if (lane == 0) {
      const double sd = (double)s / FIX_SCALE;
      const double cd = c ? (double)c : 1.0;
      out[0] = (float)(sd / cd);
    }
  }
}

extern "C" void kernel_launch(void* const* d_in, const int* in_sizes, int n_in,
                              void* d_out, int out_size, void* d_ws, size_t ws_size,
                              hipStream_t stream) {
  const float* emb  = (const float*)d_in[0];
  const int* labels = (const int*)d_in[1];
  float* out        = (float*)d_out;

  char* ws = (char*)d_ws;
  unsigned long long* part = (unsigned long long*)ws;          // 256 * 8 B
  uint32_t* gflag = (uint32_t*)(ws + 2048);                    // 256 * 4 B
  float* dg = (float*)(ws + 4096);                             // 512 * 4 B
  float* G  = (float*)(ws + 8192);                             // 1 MB

  triplet_fused<<<dim3(NBLK), dim3(512), 0, stream>>>(emb, labels, G, dg,
                                                      gflag, part, out);
}

// Round 9
// 17.173 us; speedup vs baseline: 2.3382x; 2.3382x over previous
//
#include <hip/hip_runtime.h>
#include <cstdint>

#define NPTS 512
#define DIM 256
#define NBLK (NPTS / 2)
#define TK 32
#define LDB 264             // bf16 elements per LDS row (padded: 528 B, bank offset 4/row)
#define MARGIN_F 0.2f
#define FIX_SCALE 1073741824.0   // 2^30
#define SUM_BITS 42
#define CNT_SHIFT 42
#define DONE_SHIFT 56

typedef __attribute__((ext_vector_type(8))) short bf16x8;   // 8 bf16 = 4 VGPR
typedef __attribute__((ext_vector_type(4))) float f32x4;

__device__ __forceinline__ uint32_t rotl32(uint32_t x, uint32_t r) {
  return (x << r) | (x >> (32u - r));
}

__device__ __forceinline__ ushort f2bf(float f) {   // RNE float->bf16
  uint32_t u = __float_as_uint(f);
  return (ushort)((u + 0x7FFFu + ((u >> 16) & 1u)) >> 16);
}
__device__ __forceinline__ float bf2f(ushort h) {
  return __uint_as_float(((uint32_t)h) << 16);
}

// JAX threefry2x32, key (0, 42), partitionable mode: bits = out0 ^ out1,
// counter x = (hi32(m)=0, lo32(m)=m). Verified bit-exact (absmax 0.0, r1-r6).
__device__ __forceinline__ uint32_t threefry_bits(uint32_t c1) {
  const uint32_t k0 = 0u, k1 = 42u;
  const uint32_t k2 = k0 ^ k1 ^ 0x1BD11BDAu;
  uint32_t x0 = 0u + k0;
  uint32_t x1 = c1 + k1;
#define TFR(r) { x0 += x1; x1 = rotl32(x1, r); x1 ^= x0; }
  TFR(13u) TFR(15u) TFR(26u) TFR(6u)
  x0 += k1; x1 += k2 + 1u;
  TFR(17u) TFR(29u) TFR(16u) TFR(24u)
  x0 += k2; x1 += k0 + 2u;
  TFR(13u) TFR(15u) TFR(26u) TFR(6u)
  x0 += k0; x1 += k1 + 3u;
  TFR(17u) TFR(29u) TFR(16u) TFR(24u)
  x0 += k1; x1 += k2 + 4u;
  TFR(13u) TFR(15u) TFR(26u) TFR(6u)
  x0 += k2; x1 += k0 + 5u;
#undef TFR
  return x0 ^ x1;
}

// ---- K1: Gram via bf16-split MFMA. Block b -> 32x32 tile (b>>4, b&15). ----
// G = E.E^T: split e = hi + lo (bf16 each); G ~= hi.hi^T + hi.lo^T + lo.hi^T
// (lo.lo ~ 2^-18 rel, dropped). Waves 0-3 compute one 16x16 quadrant each
// with mfma_f32_16x16x32_bf16 over K=256 (8 ksteps x 3 mfma).
// G symmetric => any C/D or A/B-role transpose is value-invariant; a
// consistent k-permutation cancels between A and B fragments.
__global__ __launch_bounds__(512) void gram_kernel(
    const float* __restrict__ emb,
    float* __restrict__ G,
    float* __restrict__ dg,
    unsigned long long* __restrict__ gsum)
{
  __shared__ __align__(16) ushort Ahi[TK][LDB];
  __shared__ __align__(16) ushort Alo[TK][LDB];
  __shared__ __align__(16) ushort Bhi[TK][LDB];
  __shared__ __align__(16) ushort Blo[TK][LDB];

  const int b = blockIdx.x;
  const int ti = b >> 4, tj = b & 15;
  const int t = threadIdx.x;
  const int wave = t >> 6;
  const int lane = t & 63;

  if (b == 0 && t == 0) *gsum = 0ull;   // replaces a memset dispatch

  // ---- stage + split-convert: 32 rows x 256 k for A and B tiles ----
  // 2048 float4 per tile / 512 threads = 4 float4 each, coalesced along k.
  #pragma unroll
  for (int q = 0; q < 4; ++q) {
    const int idx = (q << 9) + t;       // 0..2047
    const int r = idx >> 6;             // row 0..31
    const int c4 = idx & 63;            // float4 within row
    const float4 va = *reinterpret_cast<const float4*>(emb + (ti * TK + r) * DIM + c4 * 4);
    const float4 vb = (ti == tj) ? va
        : *reinterpret_cast<const float4*>(emb + (tj * TK + r) * DIM + c4 * 4);
    const float af[4] = {va.x, va.y, va.z, va.w};
    const float bf[4] = {vb.x, vb.y, vb.z, vb.w};
    #pragma unroll
    for (int e = 0; e < 4; ++e) {
      const int c = c4 * 4 + e;
      const ushort ah = f2bf(af[e]);
      Ahi[r][c] = ah;
      Alo[r][c] = f2bf(af[e] - bf2f(ah));
      const ushort bh = f2bf(bf[e]);
      Bhi[r][c] = bh;
      Blo[r][c] = f2bf(bf[e] - bf2f(bh));
    }
  }
  __syncthreads();

  // ---- MFMA phase: waves 0-3, quadrant (qr,qc) = (wave>>1, wave&1) ----
  if (wave < 4) {
    const int qr = wave >> 1, qc = wave & 1;
    const int frow = qr * 16 + (lane & 15);   // A-fragment row
    const int fcol = qc * 16 + (lane & 15);   // B-fragment col (B^T row)
    const int kg = lane >> 4;                 // k-group 0..3

    f32x4 acc = {0.f, 0.f, 0.f, 0.f};
    #pragma unroll
    for (int s = 0; s < 8; ++s) {
      const int kb = s * 32 + kg * 8;
      const bf16x8 ah = *reinterpret_cast<const bf16x8*>(&Ahi[frow][kb]);
      const bf16x8 al = *reinterpret_cast<const bf16x8*>(&Alo[frow][kb]);
      const bf16x8 bh = *reinterpret_cast<const bf16x8*>(&Bhi[fcol][kb]);
      const bf16x8 bl = *reinterpret_cast<const bf16x8*>(&Blo[fcol][kb]);
      acc = __builtin_amdgcn_mfma_f32_16x16x32_bf16(ah, bh, acc, 0, 0, 0);
      acc = __builtin_amdgcn_mfma_f32_16x16x32_bf16(ah, bl, acc, 0, 0, 0);
      acc = __builtin_amdgcn_mfma_f32_16x16x32_bf16(al, bh, acc, 0, 0, 0);
    }

    // C/D layout (m89): col = lane&15, row = (lane>>4)*4 + j
    const int lc = qc * 16 + (lane & 15);
    #pragma unroll
    for (int j = 0; j < 4; ++j) {
      const int lr = qr * 16 + (lane >> 4) * 4 + j;
      G[(ti * TK + lr) * NPTS + (tj * TK + lc)] = acc[j];
      if (ti == tj && lr == lc) dg[ti * TK + lr] = acc[j];
    }
  }
}

// ---- K2: semi-hard scan (verbatim round 6). One block per 2 anchors. ----
__global__ __launch_bounds__(512) void semihard_kernel(
    const float* __restrict__ G,
    const float* __restrict__ dg,
    const int* __restrict__ labels,
    unsigned long long* __restrict__ gsum,
    float* __restrict__ out)
{
  __shared__ float sd0[NPTS];
  __shared__ float sd1[NPTS];
  __shared__ int   slab[NPTS];
  __shared__ int   plist[256];
  __shared__ int   pcnt;
  __shared__ unsigned long long wsum[8], wcnt[8];

  const int a0 = blockIdx.x * 2;
  const int a1 = a0 + 1;
  const int t = threadIdx.x;
  const int wave = t >> 6;
  const int lane = t & 63;

  if (t == 0) pcnt = 0;

  {
    const float da0 = dg[a0];
    const float da1 = dg[a1];
    const float dt  = dg[t];
    const float g0 = G[a0 * NPTS + t];
    const float g1 = G[a1 * NPTS + t];
    slab[t] = labels[t];
    const float v0 = da0 + dt - 2.f * g0;
    const float v1 = da1 + dt - 2.f * g1;
    sd0[t] = v0 > 0.f ? v0 : 0.f;
    sd1[t] = v1 > 0.f ? v1 : 0.f;
  }
  __syncthreads();

  {
    const int lp = slab[t];
    if (t != a0 && lp == slab[a0]) { int k = atomicAdd(&pcnt, 1); plist[k] = t; }
    if (t != a1 && lp == slab[a1]) { int k = atomicAdd(&pcnt, 1); plist[k] = (1 << 16) | t; }
  }
  __syncthreads();

  unsigned long long lsum = 0ull, lcnt = 0ull;
  const int np = pcnt;
  for (int e = wave; e < np; e += 8) {
    const int ent = plist[e];
    const int ai = ent >> 16;
    const int p = ent & 0xffff;
    const float* drp = ai ? sd1 : sd0;
    const int ag = ai ? a1 : a0;
    const int la = slab[ag];
    const float dap = drp[p];
    const float hi = dap + MARGIN_F;
    const uint32_t base = ((uint32_t)ag << 18) | ((uint32_t)p << 9);

    int bestKey = -1, bestJ = 0;
    #pragma unroll
    for (int k = 0; k < 8; ++k) {
      const int j = lane + (k << 6);
      const float dj = drp[j];
      if (slab[j] != la && dj > dap && dj < hi) {
        const int key = (int)(threefry_bits(base + (uint32_t)j) >> 9);
        if (key > bestKey) { bestKey = key; bestJ = j; }
      }
    }
    #pragma unroll
    for (int m = 32; m; m >>= 1) {
      const int ok = __shfl_xor(bestKey, m);
      const int oj = __shfl_xor(bestJ, m);
      if (ok > bestKey || (ok == bestKey && oj < bestJ)) { bestKey = ok; bestJ = oj; }
    }
    if (lane == 0 && bestKey >= 0) {
      const float term = (dap - drp[bestJ]) + MARGIN_F;
      lsum += (unsigned long long)((double)term * FIX_SCALE + 0.5);
      lcnt += 1ull;
    }
  }

  if (lane == 0) { wsum[wave] = lsum; wcnt[wave] = lcnt; }
  __syncthreads();
  if (t == 0) {
    unsigned long long s = 0ull, c = 0ull;
    #pragma unroll
    for (int w = 0; w < 8; ++w) { s += wsum[w]; c += wcnt[w]; }
    const unsigned long long contrib =
        (1ull << DONE_SHIFT) | (c << CNT_SHIFT) | s;
    const unsigned long long old = atomicAdd(gsum, contrib);
    if ((old >> DONE_SHIFT) == (unsigned long long)(NBLK - 1)) {
      const unsigned long long tot = old + contrib;
      const unsigned long long sum = tot & ((1ull << SUM_BITS) - 1ull);
      const unsigned long long cnt = (tot >> CNT_SHIFT) & 0x3FFFull;
      const double sd = (double)sum / FIX_SCALE;
      const double cd = cnt ? (double)cnt : 1.0;
      out[0] = (float)(sd / cd);
    }
  }
}

extern "C" void kernel_launch(void* const* d_in, const int* in_sizes, int n_in,
                              void* d_out, int out_size, void* d_ws, size_t ws_size,
                              hipStream_t stream) {
  const float* emb  = (const float*)d_in[0];
  const int* labels = (const int*)d_in[1];
  float* out        = (float*)d_out;

  char* ws = (char*)d_ws;
  unsigned long long* gsum = (unsigned long long*)ws;          // 8 B
  float* dg = (float*)(ws + 2048);                             // 512 * 4 B
  float* G  = (float*)(ws + 8192);                             // 1 MB

  gram_kernel<<<dim3(256), dim3(512), 0, stream>>>(emb, G, dg, gsum);
  semihard_kernel<<<dim3(NBLK), dim3(512), 0, stream>>>(G, dg, labels, gsum, out);
}